// Round 3
// baseline (144.869 us; speedup 1.0000x reference)
//
#include <hip/hip_runtime.h>
#include <stdint.h>

#define BT 4096      // tokens total (8*512)
#define KC 8192      // centroids
#define DD 768       // feature dim
#define T_STRIDE 513 // rep row stride (skip token 0 per batch)
#define DELTA 20.0f  // i8 screen window: err RMS ~0.75 -> ~26 sigma margin

typedef int   v4i  __attribute__((ext_vector_type(4)));
typedef float f32x4 __attribute__((ext_vector_type(4)));

#define GLD16(gp, lp)                                                       \
  __builtin_amdgcn_global_load_lds(                                         \
      (__attribute__((address_space(1))) void*)(gp),                        \
      (__attribute__((address_space(3))) void*)(lp), 16, 0, 0)

__device__ __forceinline__ unsigned int sortable_bits(float d) {
  unsigned int bits = __float_as_uint(d);
  return (bits & 0x80000000u) ? ~bits : (bits | 0x80000000u);
}

// ------- D1: per-row absmax-quantize fp32 -> i8 + scales + exact cent norms -------
__global__ __launch_bounds__(256) void quant_kernel(
    const float* __restrict__ rep, const float* __restrict__ cent,
    int8_t* __restrict__ a8, int8_t* __restrict__ b8,
    float* __restrict__ s_a, float* __restrict__ s_b,
    float* __restrict__ norm_cent) {
  int wid  = (blockIdx.x * blockDim.x + threadIdx.x) >> 6;
  int lane = threadIdx.x & 63;
  const float4* s4;
  int8_t* dst;
  float* sdst;
  float* ndst = nullptr;
  if (wid < BT) {
    int b = wid >> 9, tt = wid & 511;
    s4 = (const float4*)(rep + (size_t)(b * T_STRIDE + 1 + tt) * DD);
    dst = a8 + (size_t)wid * DD;
    sdst = s_a + wid;
  } else {
    int k = wid - BT;
    if (k >= KC) return;
    s4 = (const float4*)(cent + (size_t)k * DD);
    dst = b8 + (size_t)k * DD;
    sdst = s_b + k;
    ndst = norm_cent + k;
  }
  float4 v[3];
  float m = 0.f, nrm = 0.f;
  #pragma unroll
  for (int i = 0; i < 3; ++i) {
    v[i] = s4[lane + i * 64];
    m = fmaxf(m, fmaxf(fmaxf(fabsf(v[i].x), fabsf(v[i].y)),
                       fmaxf(fabsf(v[i].z), fabsf(v[i].w))));
    nrm += v[i].x * v[i].x + v[i].y * v[i].y + v[i].z * v[i].z + v[i].w * v[i].w;
  }
  #pragma unroll
  for (int off = 32; off; off >>= 1) m = fmaxf(m, __shfl_xor(m, off, 64));
  const float rs = (m > 0.f) ? 127.0f / m : 0.f;
  unsigned* d32 = (unsigned*)dst;
  #pragma unroll
  for (int i = 0; i < 3; ++i) {
    int q0 = (int)rintf(v[i].x * rs);
    int q1 = (int)rintf(v[i].y * rs);
    int q2 = (int)rintf(v[i].z * rs);
    int q3 = (int)rintf(v[i].w * rs);
    unsigned pk = (unsigned)(q0 & 255) | ((unsigned)(q1 & 255) << 8) |
                  ((unsigned)(q2 & 255) << 16) | ((unsigned)(q3 & 255) << 24);
    d32[lane + i * 64] = pk;
  }
  if (ndst) {
    #pragma unroll
    for (int off = 32; off; off >>= 1) nrm += __shfl_down(nrm, off, 64);
  }
  if (lane == 0) {
    *sdst = m / 127.0f;
    if (ndst) *ndst = nrm;
  }
}

// ------- D2: i8 MFMA GEMM, 128x128 tile, ring-3 BK=64, counted vmcnt (T4) ------
// grid: (KC/128, BT/128) = (64, 32); 256 threads (4 waves, 2x2 of 64x64).
// LDS: 3 slices x (128x64 A + 128x64 B) = 48KB -> 3 blocks/CU (12 waves).
// Per slice s: vmcnt(4) [counted: slice s+1's loads stay in flight across the
// barrier, issued a full iter earlier] -> s_barrier -> 8 ds_read_b128 ->
// STAGE(s+2) -> 16 MFMA. One barrier/slice; vmcnt never drains to 0 mid-loop.
// Overwrite safety: STAGE(s+2) hits buf (s-1)%3 whose readers' lgkm waits
// preceded the barrier every wave just crossed.
// Screen distance d~ = nc_k - 2*sa_t*sb_k*idot. Emits LMin/Mask per (t, 64-cent group).
__global__ __launch_bounds__(256, 3) void mfma_i8_cand(
    const int8_t* __restrict__ a8,   // tokens [BT][DD]
    const int8_t* __restrict__ b8,   // cents  [KC][DD]
    const float* __restrict__ s_a, const float* __restrict__ s_b,
    const float* __restrict__ norm_cent,
    float* __restrict__ LMin, unsigned long long* __restrict__ Mask) {
  __shared__ __attribute__((aligned(16))) int8_t As[3][128 * 64];  // cents 24KB
  __shared__ __attribute__((aligned(16))) int8_t Bs[3][128 * 64];  // tokens 24KB

  const int tid = threadIdx.x;
  const int w = tid >> 6, l = tid & 63;
  const int bm0 = blockIdx.x * 128;  // centroid base
  const int bn0 = blockIdx.y * 128;  // token base

  // staging: instr i in {0,1}: LDS linear idx = i*256+tid -> row i*64+(tid>>2),
  // 16B slot tid&3. Global chunk = slot ^ ((row>>1)&3)  (bank swizzle; LDS dest
  // stays wave-uniform base + lane*16). (row>>1)&3 == (tid>>3)&3 for both i.
  const int srow   = tid >> 2;
  const int schunk = (tid & 3) ^ ((tid >> 3) & 3);
  const size_t gA0 = (size_t)(bm0 + srow) * DD + schunk * 16;
  const size_t gB0 = (size_t)(bn0 + srow) * DD + schunk * 16;
  const int ldst = tid * 16;

  const int wm = (w & 1) * 64;   // centroid offset within tile
  const int wn = (w >> 1) * 64;  // token offset within tile
  const int sub = l & 15, q = l >> 4;
  // read slot: global chunk q lives at slot q ^ ((row>>1)&3); for rows
  // wm+i*16+sub this is q ^ ((sub>>1)&3) independent of i and wm.
  const int rslot = (q ^ ((sub >> 1) & 3)) * 16;

  v4i acc[4][4] = {};  // [mt: cent subtile][nt: token subtile], i32 x4

#define STAGE(s)                                                             \
  do {                                                                       \
    const int b_ = (s) % 3;                                                  \
    GLD16(b8 + gA0 + (s) * 64,           As[b_] + ldst);                     \
    GLD16(b8 + gA0 + 64 * DD + (s) * 64, As[b_] + 4096 + ldst);              \
    GLD16(a8 + gB0 + (s) * 64,           Bs[b_] + ldst);                     \
    GLD16(a8 + gB0 + 64 * DD + (s) * 64, Bs[b_] + 4096 + ldst);              \
  } while (0)

  // prologue: slices 0,1 in flight
  STAGE(0);
  STAGE(1);

  #pragma unroll
  for (int s = 0; s < 12; ++s) {
    // counted wait: <=4 outstanding leaves slice s+1's 4 loads in flight,
    // guarantees slice s's landed. Tail iter drains fully.
    if (s < 11) asm volatile("s_waitcnt vmcnt(4)" ::: "memory");
    else        asm volatile("s_waitcnt vmcnt(0)" ::: "memory");
    __builtin_amdgcn_s_barrier();         // all waves' slice-s data visible
    __builtin_amdgcn_sched_barrier(0);    // pin: no LDS reads above barrier
    const int buf = s % 3;
    v4i af[4], bf[4];
    #pragma unroll
    for (int i = 0; i < 4; ++i) {
      af[i] = *(const v4i*)(As[buf] + (wm + i * 16 + sub) * 64 + rslot);
      bf[i] = *(const v4i*)(Bs[buf] + (wn + i * 16 + sub) * 64 + rslot);
    }
    if (s < 10) STAGE(s + 2);  // into buf (s-1)%3: readers done pre-barrier
    #pragma unroll
    for (int mt = 0; mt < 4; ++mt)
      #pragma unroll
      for (int nt = 0; nt < 4; ++nt)
        asm volatile("v_mfma_i32_16x16x64_i8 %0, %1, %2, %0"
                     : "+v"(acc[mt][nt])
                     : "v"(af[mt]), "v"(bf[nt]));
  }
#undef STAGE

  // cover MFMA dst latency before VALU reads (inline asm bypasses compiler hazards)
  asm volatile("s_nop 7\n\ts_nop 7\n\ts_nop 7" ::: "memory");

  // epilogue: per lane, 16 screen distances of token (nt,sub) are in-lane (mt x r)
  const int g = (bm0 >> 6) + (w & 1);   // 64-centroid group index
  float ncv[4][4], sbv[4][4];
  #pragma unroll
  for (int mt = 0; mt < 4; ++mt)
    #pragma unroll
    for (int r = 0; r < 4; ++r) {
      const int k = bm0 + wm + mt * 16 + q * 4 + r;
      ncv[mt][r] = norm_cent[k];
      sbv[mt][r] = s_b[k];
    }

  #pragma unroll
  for (int nt = 0; nt < 4; ++nt) {
    const int t = bn0 + wn + nt * 16 + sub;
    const float sa2 = 2.0f * s_a[t];
    float d[4][4];
    float dmin = 3.4e38f;
    #pragma unroll
    for (int mt = 0; mt < 4; ++mt)
      #pragma unroll
      for (int r = 0; r < 4; ++r) {
        d[mt][r] = ncv[mt][r] - sa2 * sbv[mt][r] * (float)acc[mt][nt][r];
        dmin = fminf(dmin, d[mt][r]);
      }
    // fold across the 4 q-lanes holding this token
    dmin = fminf(dmin, __shfl_xor(dmin, 16, 64));
    dmin = fminf(dmin, __shfl_xor(dmin, 32, 64));
    const float thresh = dmin + DELTA;
    unsigned long long pm = 0;
    #pragma unroll
    for (int mt = 0; mt < 4; ++mt)
      #pragma unroll
      for (int r = 0; r < 4; ++r)
        if (d[mt][r] <= thresh) pm |= 1ull << (mt * 16 + q * 4 + r);
    pm |= (unsigned long long)__shfl_xor((long long)pm, 16, 64);
    pm |= (unsigned long long)__shfl_xor((long long)pm, 32, 64);
    if (q == 0) {
      LMin[(size_t)t * 128 + g] = dmin;
      Mask[(size_t)t * 128 + g] = pm;
    }
  }
}

// ------- D3: refine, wave per token (r6-proven), exact fp32 shifted distance -------
__global__ __launch_bounds__(256) void refine_kernel(
    const float* __restrict__ LMin, const unsigned long long* __restrict__ Mask,
    const float* __restrict__ rep, const float* __restrict__ cent,
    const float* __restrict__ norm_cent,
    float* __restrict__ out_tokens, float* __restrict__ out_q) {
  const int w = threadIdx.x >> 6, l = threadIdx.x & 63;
  const int t = blockIdx.x * 4 + w;
  if (t >= BT) return;

  const float lm0 = LMin[(size_t)t * 128 + l];
  const float lm1 = LMin[(size_t)t * 128 + 64 + l];
  float v = fminf(lm0, lm1);
  #pragma unroll
  for (int off = 32; off; off >>= 1) v = fminf(v, __shfl_xor(v, off, 64));
  const float thresh = v + DELTA;
  unsigned long long gm0 = __ballot(lm0 <= thresh);
  unsigned long long gm1 = __ballot(lm1 <= thresh);

  const int b_ = t >> 9, tt = t & 511;
  const float* rrow = rep + (size_t)(b_ * T_STRIDE + 1 + tt) * DD;
  unsigned long long bestE = ~0ull;   // lane 0 authoritative

  #pragma unroll
  for (int half = 0; half < 2; ++half) {
    unsigned long long gmask = half ? gm1 : gm0;
    while (gmask) {
      const int h = __ffsll((unsigned long long)gmask) - 1;
      gmask &= gmask - 1;
      unsigned long long mask = Mask[(size_t)t * 128 + half * 64 + h];
      while (mask) {
        const int bit = __ffsll((unsigned long long)mask) - 1;
        mask &= mask - 1;
        const int k = (half * 64 + h) * 64 + bit;
        const float* crow = cent + (size_t)k * DD;
        float part = 0.f;
        #pragma unroll
        for (int j = 0; j < 12; ++j)
          part += rrow[l + j * 64] * crow[l + j * 64];
        #pragma unroll
        for (int off = 32; off; off >>= 1) part += __shfl_down(part, off, 64);
        if (l == 0) {
          float d = norm_cent[k] - 2.0f * part;   // shifted exact (r9-validated)
          unsigned long long p =
              ((unsigned long long)sortable_bits(d) << 32) | (unsigned)k;
          if (p < bestE) bestE = p;
        }
      }
    }
  }
  int kb0 = (l == 0) ? (int)(bestE & 0xFFFFFFFFull) : 0;
  const int kbest = __shfl(kb0, 0, 64);
  if (l == 0) out_tokens[t] = (float)kbest;
  const float4* src = (const float4*)(cent + (size_t)kbest * DD);
  float4* dst = (float4*)(out_q + (size_t)t * DD);
  #pragma unroll
  for (int j = 0; j < 3; ++j) dst[l + j * 64] = src[l + j * 64];
}

// ================= tiny-ws fallback: fp32 vector GEMM + argmin =================
#define FBM 64
#define FBN 64
#define FBK 16
#define FNSPLIT 16
__global__ __launch_bounds__(256) void norms_only_kernel(
    const float* __restrict__ rep, const float* __restrict__ cent,
    float* __restrict__ norm_rep, float* __restrict__ norm_cent) {
  int wid  = (blockIdx.x * blockDim.x + threadIdx.x) >> 6;
  int lane = threadIdx.x & 63;
  const float* src;
  float* nd;
  if (wid < BT) {
    int b = wid >> 9, tt = wid & 511;
    src = rep + (size_t)(b * T_STRIDE + 1 + tt) * DD;
    nd = norm_rep + wid;
  } else {
    int k = wid - BT;
    if (k >= KC) return;
    src = cent + (size_t)k * DD;
    nd = norm_cent + k;
  }
  float s = 0.f;
  for (int j = lane; j < DD; j += 64) { float v = src[j]; s += v * v; }
  #pragma unroll
  for (int off = 32; off; off >>= 1) s += __shfl_down(s, off, 64);
  if (lane == 0) *nd = s;
}

__global__ __launch_bounds__(256) void fp32_argmin_gemm(
    const float* __restrict__ rep, const float* __restrict__ cent,
    const float* __restrict__ norm_rep, const float* __restrict__ norm_cent,
    unsigned long long* __restrict__ packed) {
  __shared__ float Asf[FBK][FBM];
  __shared__ float Bsf[FBK][FBN];
  const int tid = threadIdx.x;
  const int m0  = blockIdx.x * FBM;
  const int kbase = blockIdx.y * (KC / FNSPLIT);
  const int tx = tid & 15, ty = tid >> 4;
  const int ldr = tid >> 2, ldc = (tid & 3) * 4;
  const int t_ld = m0 + ldr;
  const float* arow =
      rep + (size_t)((t_ld >> 9) * T_STRIDE + 1 + (t_ld & 511)) * DD + ldc;
  unsigned long long best[4];
  #pragma unroll
  for (int i = 0; i < 4; ++i) best[i] = ~0ull;
  float nr[4];
  #pragma unroll
  for (int i = 0; i < 4; ++i) nr[i] = norm_rep[m0 + ty * 4 + i];
  for (int nt = 0; nt < (KC / FNSPLIT) / FBN; ++nt) {
    const int n0 = kbase + nt * FBN;
    const float* brow = cent + (size_t)(n0 + ldr) * DD + ldc;
    float acc[4][4];
    #pragma unroll
    for (int i = 0; i < 4; ++i)
      #pragma unroll
      for (int j = 0; j < 4; ++j) acc[i][j] = 0.f;
    for (int d0 = 0; d0 < DD; d0 += FBK) {
      float4 av = *(const float4*)(arow + d0);
      float4 bv = *(const float4*)(brow + d0);
      __syncthreads();
      Asf[ldc + 0][ldr] = av.x; Asf[ldc + 1][ldr] = av.y;
      Asf[ldc + 2][ldr] = av.z; Asf[ldc + 3][ldr] = av.w;
      Bsf[ldc + 0][ldr] = bv.x; Bsf[ldc + 1][ldr] = bv.y;
      Bsf[ldc + 2][ldr] = bv.z; Bsf[ldc + 3][ldr] = bv.w;
      __syncthreads();
      #pragma unroll
      for (int kk = 0; kk < FBK; ++kk) {
        float4 a4 = *(const float4*)&Asf[kk][ty * 4];
        float4 b4 = *(const float4*)&Bsf[kk][tx * 4];
        float a[4] = {a4.x, a4.y, a4.z, a4.w};
        float b[4] = {b4.x, b4.y, b4.z, b4.w};
        #pragma unroll
        for (int i = 0; i < 4; ++i)
          #pragma unroll
          for (int j = 0; j < 4; ++j) acc[i][j] += a[i] * b[j];
      }
    }
    #pragma unroll
    for (int i = 0; i < 4; ++i) {
      #pragma unroll
      for (int j = 0; j < 4; ++j) {
        int k = n0 + tx * 4 + j;
        float d = (nr[i] + norm_cent[k]) - 2.0f * acc[i][j];
        unsigned long long p =
            ((unsigned long long)sortable_bits(d) << 32) | (unsigned int)k;
        if (p < best[i]) best[i] = p;
      }
    }
  }
  #pragma unroll
  for (int off = 1; off < 16; off <<= 1) {
    #pragma unroll
    for (int i = 0; i < 4; ++i) {
      unsigned long long o =
          (unsigned long long)__shfl_xor((long long)best[i], off, 64);
      if (o < best[i]) best[i] = o;
    }
  }
  if (tx == 0) {
    #pragma unroll
    for (int i = 0; i < 4; ++i)
      atomicMin(&packed[m0 + ty * 4 + i], best[i]);
  }
}

__global__ __launch_bounds__(192) void gather_kernel(
    const unsigned long long* __restrict__ packed,
    const float* __restrict__ cent,
    float* __restrict__ out_tokens, float* __restrict__ out_q) {
  int t = blockIdx.x;
  unsigned int k = (unsigned int)(packed[t] & 0xFFFFFFFFull);
  if (threadIdx.x == 0) out_tokens[t] = (float)k;
  const float4* src = (const float4*)(cent + (size_t)k * DD);
  float4* dst = (float4*)(out_q + (size_t)t * DD);
  dst[threadIdx.x] = src[threadIdx.x];
}

extern "C" void kernel_launch(void* const* d_in, const int* in_sizes, int n_in,
                              void* d_out, int out_size, void* d_ws, size_t ws_size,
                              hipStream_t stream) {
  const float* rep  = (const float*)d_in[0];   // (8,513,768) fp32
  const float* cent = (const float*)d_in[1];   // (8192,768) fp32
  float* out = (float*)d_out;                  // [tokens(4096) | quantized(4096*768)]

  // layout: a8 | b8 | LMin | Mask | s_a | s_b | norm_cent
  const size_t SZ_A8 = (size_t)BT * DD;              //  3 MiB
  const size_t SZ_B8 = (size_t)KC * DD;              //  6 MiB
  const size_t SZ_LM = (size_t)BT * 128 * 4;         //  2 MiB
  const size_t SZ_MK = (size_t)BT * 128 * 8;         //  4 MiB
  const size_t OFF_SA = SZ_A8 + SZ_B8 + SZ_LM + SZ_MK;
  const size_t OFF_SB = OFF_SA + 16384;
  const size_t OFF_NC = OFF_SB + 32768;
  const size_t WS_A   = OFF_NC + 32768;

  if (ws_size >= WS_A) {
    int8_t* a8 = (int8_t*)d_ws;
    int8_t* b8 = (int8_t*)((char*)d_ws + SZ_A8);
    float* LMin = (float*)((char*)d_ws + SZ_A8 + SZ_B8);
    unsigned long long* Mask =
        (unsigned long long*)((char*)d_ws + SZ_A8 + SZ_B8 + SZ_LM);
    float* s_a = (float*)((char*)d_ws + OFF_SA);
    float* s_b = (float*)((char*)d_ws + OFF_SB);
    float* norm_cent = (float*)((char*)d_ws + OFF_NC);

    quant_kernel<<<3072, 256, 0, stream>>>(rep, cent, a8, b8, s_a, s_b,
                                           norm_cent);
    dim3 grid(KC / 128, BT / 128);
    mfma_i8_cand<<<grid, 256, 0, stream>>>(a8, b8, s_a, s_b, norm_cent,
                                           LMin, Mask);
    refine_kernel<<<BT / 4, 256, 0, stream>>>(LMin, Mask, rep, cent,
                                              norm_cent, out, out + BT);
  } else {
    unsigned long long* packed = (unsigned long long*)d_ws;
    float* norm_rep  = (float*)((char*)d_ws + 32768);
    float* norm_cent = (float*)((char*)d_ws + 49152);

    hipMemsetAsync(packed, 0xFF, BT * sizeof(unsigned long long), stream);
    norms_only_kernel<<<3072, 256, 0, stream>>>(rep, cent, norm_rep, norm_cent);
    dim3 grid(BT / FBM, FNSPLIT);
    fp32_argmin_gemm<<<grid, 256, 0, stream>>>(rep, cent, norm_rep, norm_cent,
                                               packed);
    gather_kernel<<<BT, 192, 0, stream>>>(packed, cent, out, out + BT);
  }
}

// Round 5
// 138.971 us; speedup vs baseline: 1.0424x; 1.0424x over previous
//
#include <hip/hip_runtime.h>
#include <stdint.h>

#define BT 4096      // tokens total (8*512)
#define KC 8192      // centroids
#define DD 768       // feature dim
#define T_STRIDE 513 // rep row stride (skip token 0 per batch)
#define DELTA 20.0f  // i8 screen window: err RMS ~0.75 -> ~26 sigma margin

typedef int   v4i  __attribute__((ext_vector_type(4)));
typedef float f32x4 __attribute__((ext_vector_type(4)));

#define GLD16(gp, lp)                                                       \
  __builtin_amdgcn_global_load_lds(                                         \
      (__attribute__((address_space(1))) void*)(gp),                        \
      (__attribute__((address_space(3))) void*)(lp), 16, 0, 0)

__device__ __forceinline__ unsigned int sortable_bits(float d) {
  unsigned int bits = __float_as_uint(d);
  return (bits & 0x80000000u) ? ~bits : (bits | 0x80000000u);
}

// ------- D1: per-row absmax-quantize fp32 -> i8 + scales + exact cent norms -------
__global__ __launch_bounds__(256) void quant_kernel(
    const float* __restrict__ rep, const float* __restrict__ cent,
    int8_t* __restrict__ a8, int8_t* __restrict__ b8,
    float* __restrict__ s_a, float* __restrict__ s_b,
    float* __restrict__ norm_cent) {
  int wid  = (blockIdx.x * blockDim.x + threadIdx.x) >> 6;
  int lane = threadIdx.x & 63;
  const float4* s4;
  int8_t* dst;
  float* sdst;
  float* ndst = nullptr;
  if (wid < BT) {
    int b = wid >> 9, tt = wid & 511;
    s4 = (const float4*)(rep + (size_t)(b * T_STRIDE + 1 + tt) * DD);
    dst = a8 + (size_t)wid * DD;
    sdst = s_a + wid;
  } else {
    int k = wid - BT;
    if (k >= KC) return;
    s4 = (const float4*)(cent + (size_t)k * DD);
    dst = b8 + (size_t)k * DD;
    sdst = s_b + k;
    ndst = norm_cent + k;
  }
  float4 v[3];
  float m = 0.f, nrm = 0.f;
  #pragma unroll
  for (int i = 0; i < 3; ++i) {
    v[i] = s4[lane + i * 64];
    m = fmaxf(m, fmaxf(fmaxf(fabsf(v[i].x), fabsf(v[i].y)),
                       fmaxf(fabsf(v[i].z), fabsf(v[i].w))));
    nrm += v[i].x * v[i].x + v[i].y * v[i].y + v[i].z * v[i].z + v[i].w * v[i].w;
  }
  #pragma unroll
  for (int off = 32; off; off >>= 1) m = fmaxf(m, __shfl_xor(m, off, 64));
  const float rs = (m > 0.f) ? 127.0f / m : 0.f;
  unsigned* d32 = (unsigned*)dst;
  #pragma unroll
  for (int i = 0; i < 3; ++i) {
    int q0 = (int)rintf(v[i].x * rs);
    int q1 = (int)rintf(v[i].y * rs);
    int q2 = (int)rintf(v[i].z * rs);
    int q3 = (int)rintf(v[i].w * rs);
    unsigned pk = (unsigned)(q0 & 255) | ((unsigned)(q1 & 255) << 8) |
                  ((unsigned)(q2 & 255) << 16) | ((unsigned)(q3 & 255) << 24);
    d32[lane + i * 64] = pk;
  }
  if (ndst) {
    #pragma unroll
    for (int off = 32; off; off >>= 1) nrm += __shfl_down(nrm, off, 64);
  }
  if (lane == 0) {
    *sdst = m / 127.0f;
    if (ndst) *ndst = nrm;
  }
}

// ------- D2: i8 MFMA GEMM, 256x256, faithful 8-phase counted-vmcnt (T3+T4+T5) ---
// 512 thr = 8 waves (2M x 4N); per-wave out 128 cents x 64 tokens; acc[8][4].
// LDS: 2 buf x (32KB A + 32KB B) = 128KB, 1 blk/CU. 6 K-tiles (BK=128B), 2/iter.
// Iter j (tiles u=2j in buf0, u+1 in buf1), phases:
//  P1: rd A(mq0,k0)+B(k0) buf0 | stage A0(u+1)->buf1 | SYNC | MM
//  P2: rd A(mq1,k0)            | stage A1(u+1)->buf1 | SYNC | MM
//  P3: rd A(mq0,k1)+B(k1)      | --                  | SYNC | MM   (buf0-B retires)
//  P4: rd A(mq1,k1)            | stage B01(u+2)->buf0 | vmcnt(4) SYNC | MM
//  P5-P8: same on buf1, staging A01(u+2)->buf0 (P5,P6), B01(u+3)->buf1 (P8),
//         vmcnt(4) at P8. vmcnt NEVER 0 mid-loop (T4); tail drains.
// Retirement proof: every STAGE lands >=2 barriers after its region's last read.
__global__ __launch_bounds__(512, 1) void mfma_i8_cand(
    const int8_t* __restrict__ a8,   // tokens [BT][DD]
    const int8_t* __restrict__ b8,   // cents  [KC][DD]
    const float* __restrict__ s_a, const float* __restrict__ s_b,
    const float* __restrict__ norm_cent,
    float* __restrict__ LMin, unsigned long long* __restrict__ Mask) {
  __shared__ __attribute__((aligned(16))) int8_t As[2][256 * 128];  // cents 64KB
  __shared__ __attribute__((aligned(16))) int8_t Bs[2][256 * 128];  // tokens 64KB

  const int tid = threadIdx.x;
  const int w = tid >> 6, l = tid & 63;
  const int bm0 = blockIdx.x * 256;  // centroid base
  const int bn0 = blockIdx.y * 256;  // token base

  // staging: one GLD16 instr covers 64 rows x 128B (512 thr x 16B). thread ->
  // row (tid>>3), chunk (tid&7)^(row&7) (XOR swizzle; LDS dest = linear tid*16).
  const int srow   = tid >> 3;
  const int schunk = (tid & 7) ^ (srow & 7);
  const size_t gA0 = (size_t)(bm0 + srow) * DD + schunk * 16;
  const size_t gB0 = (size_t)(bn0 + srow) * DD + schunk * 16;
  const int ls = tid * 16;

  const int wm = (w >> 2) * 128;  // wave M-half (2 M-waves)
  const int wn = (w & 3) * 64;    // wave N-quarter (4 N-waves)
  const int sub = l & 15, q = l >> 4;
  // read slot for k-chunk (q+4*kk), unswizzled by row&7 == sub&7
  const int rs0 = ((q)     ^ (sub & 7)) * 16;
  const int rs1 = ((q + 4) ^ (sub & 7)) * 16;

  v4i acc[8][4] = {};  // [M-frag 0..7][N-frag 0..3]

#define STG_A(bf, h, kt)                                                      \
  do {                                                                        \
    GLD16(b8 + gA0 + (size_t)((h) * 128 + 0)  * DD + (kt) * 128,              \
          As[bf] + (h) * 16384 + 0 + ls);                                     \
    GLD16(b8 + gA0 + (size_t)((h) * 128 + 64) * DD + (kt) * 128,              \
          As[bf] + (h) * 16384 + 8192 + ls);                                  \
  } while (0)
#define STG_B(bf, h, kt)                                                      \
  do {                                                                        \
    GLD16(a8 + gB0 + (size_t)((h) * 128 + 0)  * DD + (kt) * 128,              \
          Bs[bf] + (h) * 16384 + 0 + ls);                                     \
    GLD16(a8 + gB0 + (size_t)((h) * 128 + 64) * DD + (kt) * 128,              \
          Bs[bf] + (h) * 16384 + 8192 + ls);                                  \
  } while (0)

#define LDA4(dst, bf, mq, kk)                                                 \
  do {                                                                        \
    _Pragma("unroll") for (int i_ = 0; i_ < 4; ++i_) {                        \
      const int r_ = wm + (mq) * 64 + i_ * 16 + sub;                          \
      dst[i_] = *(const v4i*)(As[bf] + r_ * 128 + ((kk) ? rs1 : rs0));        \
    }                                                                         \
  } while (0)
#define LDB4(dst, bf, kk)                                                     \
  do {                                                                        \
    _Pragma("unroll") for (int i_ = 0; i_ < 4; ++i_) {                        \
      const int r_ = wn + i_ * 16 + sub;                                      \
      dst[i_] = *(const v4i*)(Bs[bf] + r_ * 128 + ((kk) ? rs1 : rs0));        \
    }                                                                         \
  } while (0)

#define MM(mh, A_, B_)                                                        \
  do {                                                                        \
    __builtin_amdgcn_s_setprio(1);                                            \
    _Pragma("unroll") for (int mt_ = 0; mt_ < 4; ++mt_)                       \
        _Pragma("unroll") for (int nt_ = 0; nt_ < 4; ++nt_)                   \
            asm volatile("v_mfma_i32_16x16x64_i8 %0, %1, %2, %0"              \
                         : "+v"(acc[(mh) * 4 + mt_][nt_])                     \
                         : "v"(A_[mt_]), "v"(B_[nt_]));                       \
    __builtin_amdgcn_s_setprio(0);                                            \
  } while (0)

#define SYNC()                                                                \
  do {                                                                        \
    __builtin_amdgcn_s_barrier();                                             \
    asm volatile("s_waitcnt lgkmcnt(0)" ::: "memory");                        \
    __builtin_amdgcn_sched_barrier(0);                                        \
  } while (0)
#define POST() __builtin_amdgcn_s_barrier()

  // prologue: tile0 (8 loads, buf0) + tile1's B (4 loads, buf1); counted wait
  STG_A(0, 0, 0); STG_A(0, 1, 0); STG_B(0, 0, 0); STG_B(0, 1, 0);
  STG_B(1, 0, 1); STG_B(1, 1, 1);
  asm volatile("s_waitcnt vmcnt(4)" ::: "memory");  // tile0 landed, tile1-B in flight
  __builtin_amdgcn_s_barrier();

  #pragma unroll
  for (int j = 0; j < 3; ++j) {
    const int u = 2 * j;
    v4i a0[4], a1[4], b0v[4], b1v[4];
    // P1 (tile u: mq0,k0)
    LDA4(a0, 0, 0, 0); LDB4(b0v, 0, 0);
    STG_A(1, 0, u + 1);
    SYNC(); MM(0, a0, b0v); POST();
    // P2 (mq1,k0)
    LDA4(a1, 0, 1, 0);
    STG_A(1, 1, u + 1);
    SYNC(); MM(1, a1, b0v); POST();
    // P3 (mq0,k1) — buf0-B retires after these reads
    LDA4(a0, 0, 0, 1); LDB4(b1v, 0, 1);
    SYNC(); MM(0, a0, b1v); POST();
    // P4 (mq1,k1) — buf0-A retires; counted wait covers tile u+1
    LDA4(a1, 0, 1, 1);
    if (j < 2) {
      STG_B(0, 0, u + 2); STG_B(0, 1, u + 2);
      asm volatile("s_waitcnt vmcnt(4)" ::: "memory");  // thru A1(u+1)
    } else {
      asm volatile("s_waitcnt vmcnt(0)" ::: "memory");  // tail drain
    }
    SYNC(); MM(1, a1, b1v); POST();
    // P5 (tile u+1: mq0,k0)
    LDA4(a0, 1, 0, 0); LDB4(b0v, 1, 0);
    if (j < 2) STG_A(0, 0, u + 2);
    SYNC(); MM(0, a0, b0v); POST();
    // P6 (mq1,k0)
    LDA4(a1, 1, 1, 0);
    if (j < 2) STG_A(0, 1, u + 2);
    SYNC(); MM(1, a1, b0v); POST();
    // P7 (mq0,k1) — buf1-B retires
    LDA4(a0, 1, 0, 1); LDB4(b1v, 1, 1);
    SYNC(); MM(0, a0, b1v); POST();
    // P8 (mq1,k1) — counted wait covers tile u+2
    LDA4(a1, 1, 1, 1);
    if (j < 2) {
      STG_B(1, 0, u + 3); STG_B(1, 1, u + 3);
      asm volatile("s_waitcnt vmcnt(4)" ::: "memory");  // thru A1(u+2)
    }
    SYNC(); MM(1, a1, b1v); POST();
  }
#undef STG_A
#undef STG_B
#undef LDA4
#undef LDB4
#undef MM
#undef SYNC
#undef POST

  // cover MFMA dst latency before VALU reads (inline asm bypasses compiler hazards)
  asm volatile("s_nop 7\n\ts_nop 7\n\ts_nop 7" ::: "memory");

  // epilogue (R2-verified at 512 thr): per lane, 4 token subtiles x 32 screen
  // distances (8 mt x 4 r) spanning two 64-cent groups per wave M-half.
  #pragma unroll
  for (int half = 0; half < 2; ++half) {
    const int g = ((bm0 + wm) >> 6) + half;
    float nc[4][4], sb2[4][4];
    #pragma unroll
    for (int mt = 0; mt < 4; ++mt)
      #pragma unroll
      for (int r = 0; r < 4; ++r) {
        const int k = bm0 + wm + (half * 4 + mt) * 16 + q * 4 + r;
        nc[mt][r] = norm_cent[k];
        sb2[mt][r] = 2.0f * s_b[k];
      }
    #pragma unroll
    for (int nt = 0; nt < 4; ++nt) {
      const int t = bn0 + wn + nt * 16 + sub;
      const float sa = s_a[t];
      float d[4][4];
      float dmin = 3.4e38f;
      #pragma unroll
      for (int mt = 0; mt < 4; ++mt)
        #pragma unroll
        for (int r = 0; r < 4; ++r) {
          d[mt][r] = nc[mt][r] - sa * sb2[mt][r] * (float)acc[half * 4 + mt][nt][r];
          dmin = fminf(dmin, d[mt][r]);
        }
      dmin = fminf(dmin, __shfl_xor(dmin, 16, 64));
      dmin = fminf(dmin, __shfl_xor(dmin, 32, 64));
      const float thresh = dmin + DELTA;
      unsigned long long pm = 0;
      #pragma unroll
      for (int mt = 0; mt < 4; ++mt)
        #pragma unroll
        for (int r = 0; r < 4; ++r)
          if (d[mt][r] <= thresh) pm |= 1ull << (mt * 16 + q * 4 + r);
      pm |= (unsigned long long)__shfl_xor((long long)pm, 16, 64);
      pm |= (unsigned long long)__shfl_xor((long long)pm, 32, 64);
      if (q == 0) {
        LMin[(size_t)t * 128 + g] = dmin;
        Mask[(size_t)t * 128 + g] = pm;
      }
    }
  }
}

// ------- D3: refine, wave per token (r6-proven), exact fp32 shifted distance -------
__global__ __launch_bounds__(256) void refine_kernel(
    const float* __restrict__ LMin, const unsigned long long* __restrict__ Mask,
    const float* __restrict__ rep, const float* __restrict__ cent,
    const float* __restrict__ norm_cent,
    float* __restrict__ out_tokens, float* __restrict__ out_q) {
  const int w = threadIdx.x >> 6, l = threadIdx.x & 63;
  const int t = blockIdx.x * 4 + w;
  if (t >= BT) return;

  const float lm0 = LMin[(size_t)t * 128 + l];
  const float lm1 = LMin[(size_t)t * 128 + 64 + l];
  float v = fminf(lm0, lm1);
  #pragma unroll
  for (int off = 32; off; off >>= 1) v = fminf(v, __shfl_xor(v, off, 64));
  const float thresh = v + DELTA;
  unsigned long long gm0 = __ballot(lm0 <= thresh);
  unsigned long long gm1 = __ballot(lm1 <= thresh);

  const int b_ = t >> 9, tt = t & 511;
  const float* rrow = rep + (size_t)(b_ * T_STRIDE + 1 + tt) * DD;
  unsigned long long bestE = ~0ull;   // lane 0 authoritative

  #pragma unroll
  for (int half = 0; half < 2; ++half) {
    unsigned long long gmask = half ? gm1 : gm0;
    while (gmask) {
      const int h = __ffsll((unsigned long long)gmask) - 1;
      gmask &= gmask - 1;
      unsigned long long mask = Mask[(size_t)t * 128 + half * 64 + h];
      while (mask) {
        const int bit = __ffsll((unsigned long long)mask) - 1;
        mask &= mask - 1;
        const int k = (half * 64 + h) * 64 + bit;
        const float* crow = cent + (size_t)k * DD;
        float part = 0.f;
        #pragma unroll
        for (int j = 0; j < 12; ++j)
          part += rrow[l + j * 64] * crow[l + j * 64];
        #pragma unroll
        for (int off = 32; off; off >>= 1) part += __shfl_down(part, off, 64);
        if (l == 0) {
          float d = norm_cent[k] - 2.0f * part;   // shifted exact (r9-validated)
          unsigned long long p =
              ((unsigned long long)sortable_bits(d) << 32) | (unsigned)k;
          if (p < bestE) bestE = p;
        }
      }
    }
  }
  int kb0 = (l == 0) ? (int)(bestE & 0xFFFFFFFFull) : 0;
  const int kbest = __shfl(kb0, 0, 64);
  if (l == 0) out_tokens[t] = (float)kbest;
  const float4* src = (const float4*)(cent + (size_t)kbest * DD);
  float4* dst = (float4*)(out_q + (size_t)t * DD);
  #pragma unroll
  for (int j = 0; j < 3; ++j) dst[l + j * 64] = src[l + j * 64];
}

// ================= tiny-ws fallback: fp32 vector GEMM + argmin =================
#define FBM 64
#define FBN 64
#define FBK 16
#define FNSPLIT 16
__global__ __launch_bounds__(256) void norms_only_kernel(
    const float* __restrict__ rep, const float* __restrict__ cent,
    float* __restrict__ norm_rep, float* __restrict__ norm_cent) {
  int wid  = (blockIdx.x * blockDim.x + threadIdx.x) >> 6;
  int lane = threadIdx.x & 63;
  const float* src;
  float* nd;
  if (wid < BT) {
    int b = wid >> 9, tt = wid & 511;
    src = rep + (size_t)(b * T_STRIDE + 1 + tt) * DD;
    nd = norm_rep + wid;
  } else {
    int k = wid - BT;
    if (k >= KC) return;
    src = cent + (size_t)k * DD;
    nd = norm_cent + k;
  }
  float s = 0.f;
  for (int j = lane; j < DD; j += 64) { float v = src[j]; s += v * v; }
  #pragma unroll
  for (int off = 32; off; off >>= 1) s += __shfl_down(s, off, 64);
  if (lane == 0) *nd = s;
}

__global__ __launch_bounds__(256) void fp32_argmin_gemm(
    const float* __restrict__ rep, const float* __restrict__ cent,
    const float* __restrict__ norm_rep, const float* __restrict__ norm_cent,
    unsigned long long* __restrict__ packed) {
  __shared__ float Asf[FBK][FBM];
  __shared__ float Bsf[FBK][FBN];
  const int tid = threadIdx.x;
  const int m0  = blockIdx.x * FBM;
  const int kbase = blockIdx.y * (KC / FNSPLIT);
  const int tx = tid & 15, ty = tid >> 4;
  const int ldr = tid >> 2, ldc = (tid & 3) * 4;
  const int t_ld = m0 + ldr;
  const float* arow =
      rep + (size_t)((t_ld >> 9) * T_STRIDE + 1 + (t_ld & 511)) * DD + ldc;
  unsigned long long best[4];
  #pragma unroll
  for (int i = 0; i < 4; ++i) best[i] = ~0ull;
  float nr[4];
  #pragma unroll
  for (int i = 0; i < 4; ++i) nr[i] = norm_rep[m0 + ty * 4 + i];
  for (int nt = 0; nt < (KC / FNSPLIT) / FBN; ++nt) {
    const int n0 = kbase + nt * FBN;
    const float* brow = cent + (size_t)(n0 + ldr) * DD + ldc;
    float acc[4][4];
    #pragma unroll
    for (int i = 0; i < 4; ++i)
      #pragma unroll
      for (int j = 0; j < 4; ++j) acc[i][j] = 0.f;
    for (int d0 = 0; d0 < DD; d0 += FBK) {
      float4 av = *(const float4*)(arow + d0);
      float4 bv = *(const float4*)(brow + d0);
      __syncthreads();
      Asf[ldc + 0][ldr] = av.x; Asf[ldc + 1][ldr] = av.y;
      Asf[ldc + 2][ldr] = av.z; Asf[ldc + 3][ldr] = av.w;
      Bsf[ldc + 0][ldr] = bv.x; Bsf[ldc + 1][ldr] = bv.y;
      Bsf[ldc + 2][ldr] = bv.z; Bsf[ldc + 3][ldr] = bv.w;
      __syncthreads();
      #pragma unroll
      for (int kk = 0; kk < FBK; ++kk) {
        float4 a4 = *(const float4*)&Asf[kk][ty * 4];
        float4 b4 = *(const float4*)&Bsf[kk][tx * 4];
        float a[4] = {a4.x, a4.y, a4.z, a4.w};
        float b[4] = {b4.x, b4.y, b4.z, b4.w};
        #pragma unroll
        for (int i = 0; i < 4; ++i)
          #pragma unroll
          for (int j = 0; j < 4; ++j) acc[i][j] += a[i] * b[j];
      }
    }
    #pragma unroll
    for (int i = 0; i < 4; ++i) {
      #pragma unroll
      for (int j = 0; j < 4; ++j) {
        int k = n0 + tx * 4 + j;
        float d = (nr[i] + norm_cent[k]) - 2.0f * acc[i][j];
        unsigned long long p =
            ((unsigned long long)sortable_bits(d) << 32) | (unsigned int)k;
        if (p < best[i]) best[i] = p;
      }
    }
  }
  #pragma unroll
  for (int off = 1; off < 16; off <<= 1) {
    #pragma unroll
    for (int i = 0; i < 4; ++i) {
      unsigned long long o =
          (unsigned long long)__shfl_xor((long long)best[i], off, 64);
      if (o < best[i]) best[i] = o;
    }
  }
  if (tx == 0) {
    #pragma unroll
    for (int i = 0; i < 4; ++i)
      atomicMin(&packed[m0 + ty * 4 + i], best[i]);
  }
}

__global__ __launch_bounds__(192) void gather_kernel(
    const unsigned long long* __restrict__ packed,
    const float* __restrict__ cent,
    float* __restrict__ out_tokens, float* __restrict__ out_q) {
  int t = blockIdx.x;
  unsigned int k = (unsigned int)(packed[t] & 0xFFFFFFFFull);
  if (threadIdx.x == 0) out_tokens[t] = (float)k;
  const float4* src = (const float4*)(cent + (size_t)k * DD);
  float4* dst = (float4*)(out_q + (size_t)t * DD);
  dst[threadIdx.x] = src[threadIdx.x];
}

extern "C" void kernel_launch(void* const* d_in, const int* in_sizes, int n_in,
                              void* d_out, int out_size, void* d_ws, size_t ws_size,
                              hipStream_t stream) {
  const float* rep  = (const float*)d_in[0];   // (8,513,768) fp32
  const float* cent = (const float*)d_in[1];   // (8192,768) fp32
  float* out = (float*)d_out;                  // [tokens(4096) | quantized(4096*768)]

  // layout: a8 | b8 | LMin | Mask | s_a | s_b | norm_cent
  const size_t SZ_A8 = (size_t)BT * DD;              //  3 MiB
  const size_t SZ_B8 = (size_t)KC * DD;              //  6 MiB
  const size_t SZ_LM = (size_t)BT * 128 * 4;         //  2 MiB
  const size_t SZ_MK = (size_t)BT * 128 * 8;         //  4 MiB
  const size_t OFF_SA = SZ_A8 + SZ_B8 + SZ_LM + SZ_MK;
  const size_t OFF_SB = OFF_SA + 16384;
  const size_t OFF_NC = OFF_SB + 32768;
  const size_t WS_A   = OFF_NC + 32768;

  if (ws_size >= WS_A) {
    int8_t* a8 = (int8_t*)d_ws;
    int8_t* b8 = (int8_t*)((char*)d_ws + SZ_A8);
    float* LMin = (float*)((char*)d_ws + SZ_A8 + SZ_B8);
    unsigned long long* Mask =
        (unsigned long long*)((char*)d_ws + SZ_A8 + SZ_B8 + SZ_LM);
    float* s_a = (float*)((char*)d_ws + OFF_SA);
    float* s_b = (float*)((char*)d_ws + OFF_SB);
    float* norm_cent = (float*)((char*)d_ws + OFF_NC);

    quant_kernel<<<3072, 256, 0, stream>>>(rep, cent, a8, b8, s_a, s_b,
                                           norm_cent);
    dim3 grid(KC / 256, BT / 256);
    mfma_i8_cand<<<grid, 512, 0, stream>>>(a8, b8, s_a, s_b, norm_cent,
                                           LMin, Mask);
    refine_kernel<<<BT / 4, 256, 0, stream>>>(LMin, Mask, rep, cent,
                                              norm_cent, out, out + BT);
  } else {
    unsigned long long* packed = (unsigned long long*)d_ws;
    float* norm_rep  = (float*)((char*)d_ws + 32768);
    float* norm_cent = (float*)((char*)d_ws + 49152);

    hipMemsetAsync(packed, 0xFF, BT * sizeof(unsigned long long), stream);
    norms_only_kernel<<<3072, 256, 0, stream>>>(rep, cent, norm_rep, norm_cent);
    dim3 grid(BT / FBM, FNSPLIT);
    fp32_argmin_gemm<<<grid, 256, 0, stream>>>(rep, cent, norm_rep, norm_cent,
                                               packed);
    gather_kernel<<<BT, 192, 0, stream>>>(packed, cent, out, out + BT);
  }
}